// Round 3
// baseline (33666.046 us; speedup 1.0000x reference)
//
#include <hip/hip_runtime.h>
#include <hip/hip_bf16.h>

#define N_NODES 100000
#define N_EDGES 320000
#define HID 256
#define NGAUSS 50
#define NLAYERS 6
#define PROJ 256

typedef unsigned short ushortT;
typedef unsigned int uintT;

enum { MODE_PLAIN = 0, MODE_BIAS_SSP = 1, MODE_BIAS_RESID = 2, MODE_PROJ_LN = 3 };

// ---------------------------------------------------------------------------
__device__ __forceinline__ float sspf(float x) {
  return fmaxf(x, 0.0f) + log1pf(expf(-fabsf(x))) - 0.69314718055994530942f;
}

__device__ __forceinline__ float bf2f(ushortT u) {
  union { uintT i; float f; } c;
  c.i = ((uintT)u) << 16;
  return c.f;
}

__device__ __forceinline__ ushortT f2bf(float f) {
  union { float f; uintT i; } c;
  c.f = f;
  uintT i = c.i;
  uintT r = i + 0x7FFFu + ((i >> 16) & 1u);  // RNE
  return (ushortT)(r >> 16);
}

__device__ __forceinline__ void load16f(float (&b)[16], const float* __restrict__ p) {
  const float4 v0 = *(const float4*)(p + 0);
  const float4 v1 = *(const float4*)(p + 4);
  const float4 v2 = *(const float4*)(p + 8);
  const float4 v3 = *(const float4*)(p + 12);
  b[0] = v0.x;  b[1] = v0.y;  b[2] = v0.z;  b[3] = v0.w;
  b[4] = v1.x;  b[5] = v1.y;  b[6] = v1.z;  b[7] = v1.w;
  b[8] = v2.x;  b[9] = v2.y;  b[10] = v2.z; b[11] = v2.w;
  b[12] = v3.x; b[13] = v3.y; b[14] = v3.z; b[15] = v3.w;
}

__device__ __forceinline__ void load16bf(float (&b)[16], const ushortT* __restrict__ p) {
  const uint4 u0 = *(const uint4*)(p + 0);
  const uint4 u1 = *(const uint4*)(p + 8);
  b[0]  = bf2f(u0.x & 0xFFFF); b[1]  = bf2f(u0.x >> 16);
  b[2]  = bf2f(u0.y & 0xFFFF); b[3]  = bf2f(u0.y >> 16);
  b[4]  = bf2f(u0.z & 0xFFFF); b[5]  = bf2f(u0.z >> 16);
  b[6]  = bf2f(u0.w & 0xFFFF); b[7]  = bf2f(u0.w >> 16);
  b[8]  = bf2f(u1.x & 0xFFFF); b[9]  = bf2f(u1.x >> 16);
  b[10] = bf2f(u1.y & 0xFFFF); b[11] = bf2f(u1.y >> 16);
  b[12] = bf2f(u1.z & 0xFFFF); b[13] = bf2f(u1.z >> 16);
  b[14] = bf2f(u1.w & 0xFFFF); b[15] = bf2f(u1.w >> 16);
}

// dtype-dispatched 16-element load / store
__device__ __forceinline__ void load16a(float (&b)[16], const float* p) { load16f(b, p); }
__device__ __forceinline__ void load16a(float (&b)[16], const ushortT* p) { load16bf(b, p); }

__device__ __forceinline__ void store16c(float* __restrict__ p, const float (&v)[16]) {
  *(float4*)(p + 0)  = make_float4(v[0], v[1], v[2], v[3]);
  *(float4*)(p + 4)  = make_float4(v[4], v[5], v[6], v[7]);
  *(float4*)(p + 8)  = make_float4(v[8], v[9], v[10], v[11]);
  *(float4*)(p + 12) = make_float4(v[12], v[13], v[14], v[15]);
}
__device__ __forceinline__ void store16c(ushortT* __restrict__ p, const float (&v)[16]) {
  uint4 u0, u1;
  u0.x = (uintT)f2bf(v[0])  | ((uintT)f2bf(v[1])  << 16);
  u0.y = (uintT)f2bf(v[2])  | ((uintT)f2bf(v[3])  << 16);
  u0.z = (uintT)f2bf(v[4])  | ((uintT)f2bf(v[5])  << 16);
  u0.w = (uintT)f2bf(v[6])  | ((uintT)f2bf(v[7])  << 16);
  u1.x = (uintT)f2bf(v[8])  | ((uintT)f2bf(v[9])  << 16);
  u1.y = (uintT)f2bf(v[10]) | ((uintT)f2bf(v[11]) << 16);
  u1.z = (uintT)f2bf(v[12]) | ((uintT)f2bf(v[13]) << 16);
  u1.w = (uintT)f2bf(v[14]) | ((uintT)f2bf(v[15]) << 16);
  *(uint4*)(p + 0) = u0;
  *(uint4*)(p + 8) = u1;
}

// acc[j] += a * w[j]; w wave-uniform fp32 weights -> scalar loads
__device__ __forceinline__ void fma16(float (&ac)[16], const float a, const float* __restrict__ w) {
  const float4 w0 = *(const float4*)(w + 0);
  const float4 w1 = *(const float4*)(w + 4);
  const float4 w2 = *(const float4*)(w + 8);
  const float4 w3 = *(const float4*)(w + 12);
  ac[0]  = fmaf(a, w0.x, ac[0]);  ac[1]  = fmaf(a, w0.y, ac[1]);
  ac[2]  = fmaf(a, w0.z, ac[2]);  ac[3]  = fmaf(a, w0.w, ac[3]);
  ac[4]  = fmaf(a, w1.x, ac[4]);  ac[5]  = fmaf(a, w1.y, ac[5]);
  ac[6]  = fmaf(a, w1.z, ac[6]);  ac[7]  = fmaf(a, w1.w, ac[7]);
  ac[8]  = fmaf(a, w2.x, ac[8]);  ac[9]  = fmaf(a, w2.y, ac[9]);
  ac[10] = fmaf(a, w2.z, ac[10]); ac[11] = fmaf(a, w2.w, ac[11]);
  ac[12] = fmaf(a, w3.x, ac[12]); ac[13] = fmaf(a, w3.y, ac[13]);
  ac[14] = fmaf(a, w3.z, ac[14]); ac[15] = fmaf(a, w3.w, ac[15]);
}

__device__ __forceinline__ void atomic_add_bf16x2(uintT* p, float v0, float v1) {
  uintT old = __atomic_load_n(p, __ATOMIC_RELAXED);
  while (true) {
    float lo = bf2f(old & 0xFFFF) + v0;
    float hi = bf2f(old >> 16) + v1;
    uintT nw = (uintT)f2bf(lo) | ((uintT)f2bf(hi) << 16);
    uintT prev = atomicCAS(p, old, nw);
    if (prev == old) break;
    old = prev;
  }
}

// ---------------------------------------------------------------------------
// Embedding gather: h[n][c] = emb[z[n]][c]   (HT = float or bf16)
template <typename HT>
__global__ __launch_bounds__(256) void embed_k(const int* __restrict__ z,
                                               const float* __restrict__ emb,
                                               HT* __restrict__ h) {
  int idx = blockIdx.x * 256 + threadIdx.x;
  if (idx >= N_NODES * HID) return;
  int n = idx >> 8;
  int c = idx & 255;
  float v = emb[z[n] * HID + c];
  if constexpr (__is_same(HT, float)) h[idx] = v;
  else h[idx] = f2bf(v);
}

// ---------------------------------------------------------------------------
// Row-wave GEMM: C[M,256] = f(A[M,256] @ W[256,256] ...)
// AT: activation dtype (float|bf16). CT: output/resid dtype.
// MODE_PROJ_LN: fused LayerNorm+SiLU epilogue, writes float32 to outF.
template <int MODE, typename AT, typename CT>
__global__ __launch_bounds__(256) void gemm256(const AT* __restrict__ A,
                                               const float* __restrict__ W,
                                               const float* __restrict__ bias,
                                               const CT* __restrict__ resid,
                                               CT* __restrict__ C,
                                               float* __restrict__ outF, int M,
                                               const float* __restrict__ ln_g,
                                               const float* __restrict__ ln_b) {
  __shared__ float As[64 * 132];  // 33792 B, stride 132 (odd*4) for b128 banks
  __shared__ float rsum[4][64];
  __shared__ float rsq[4][64];
  const int tid = threadIdx.x;
  const int m0 = blockIdx.x * 64;
  const int wave = __builtin_amdgcn_readfirstlane(tid >> 6);
  const int lane = tid & 63;

  float acc[4][16];
#pragma unroll
  for (int nc = 0; nc < 4; ++nc)
#pragma unroll
    for (int j = 0; j < 16; ++j) acc[nc][j] = 0.0f;

#pragma unroll 1
  for (int half = 0; half < 2; ++half) {
    if (half) __syncthreads();
    // stage A[m0..m0+63][half*128..+128) into LDS as fp32
    if constexpr (__is_same(AT, float)) {
#pragma unroll
      for (int i = 0; i < 8; ++i) {
        int f4 = i * 256 + tid;           // [0,2048)
        int r = f4 >> 5, c4 = f4 & 31;
        int m = m0 + r;
        float4 v = make_float4(0.f, 0.f, 0.f, 0.f);
        if (m < M) v = *(const float4*)(A + (size_t)m * HID + half * 128 + c4 * 4);
        *(float4*)&As[r * 132 + c4 * 4] = v;
      }
    } else {
#pragma unroll
      for (int i = 0; i < 4; ++i) {
        int idx = i * 256 + tid;          // [0,1024)
        int r = idx >> 4, c8 = idx & 15;  // row, 8-bf16 chunk
        int m = m0 + r;
        uint4 u = make_uint4(0, 0, 0, 0);
        if (m < M) u = *(const uint4*)(A + (size_t)m * HID + half * 128 + c8 * 8);
        float* dst = &As[r * 132 + c8 * 8];
        dst[0] = bf2f(u.x & 0xFFFF); dst[1] = bf2f(u.x >> 16);
        dst[2] = bf2f(u.y & 0xFFFF); dst[3] = bf2f(u.y >> 16);
        dst[4] = bf2f(u.z & 0xFFFF); dst[5] = bf2f(u.z >> 16);
        dst[6] = bf2f(u.w & 0xFFFF); dst[7] = bf2f(u.w >> 16);
      }
    }
    __syncthreads();
    const float4* Arow = (const float4*)&As[lane * 132];
#pragma unroll 2
    for (int k4 = 0; k4 < 32; ++k4) {
      float4 a = Arow[k4];
      const float* Wk = W + (half * 128 + k4 * 4) * HID;
#pragma unroll
      for (int nc = 0; nc < 4; ++nc) {
        const float* wp = Wk + wave * 64 + nc * 16;
        fma16(acc[nc], a.x, wp);
        fma16(acc[nc], a.y, wp + HID);
        fma16(acc[nc], a.z, wp + 2 * HID);
        fma16(acc[nc], a.w, wp + 3 * HID);
      }
    }
  }

  const int m = m0 + lane;

  if constexpr (MODE == MODE_PROJ_LN) {
    // p = acc + bias; LN over the 256-col row (4 waves x 64 cols) + SiLU
    float psum = 0.0f, psq = 0.0f;
#pragma unroll
    for (int nc = 0; nc < 4; ++nc) {
      float bb[16];
      load16f(bb, bias + wave * 64 + nc * 16);
#pragma unroll
      for (int j = 0; j < 16; ++j) {
        float v = acc[nc][j] + bb[j];
        acc[nc][j] = v;
        psum += v;
        psq = fmaf(v, v, psq);
      }
    }
    rsum[wave][lane] = psum;
    rsq[wave][lane] = psq;
    __syncthreads();
    float s = rsum[0][lane] + rsum[1][lane] + rsum[2][lane] + rsum[3][lane];
    float q = rsq[0][lane] + rsq[1][lane] + rsq[2][lane] + rsq[3][lane];
    float mu = s * (1.0f / 256.0f);
    float var = fmaxf(q * (1.0f / 256.0f) - mu * mu, 0.0f);
    float rs = rsqrtf(var + 1e-5f);
    if (m < M) {
#pragma unroll
      for (int nc = 0; nc < 4; ++nc) {
        const int c0 = wave * 64 + nc * 16;
        float gg[16], b2[16];
        load16f(gg, ln_g + c0);
        load16f(b2, ln_b + c0);
        float out[16];
#pragma unroll
        for (int j = 0; j < 16; ++j) {
          float y = fmaf((acc[nc][j] - mu) * rs, gg[j], b2[j]);
          out[j] = y * (1.0f / (1.0f + expf(-y)));  // SiLU
        }
        store16c(outF + (size_t)m * HID + c0, out);  // float32 final output
      }
    }
  } else {
    if (m < M) {
#pragma unroll
      for (int nc = 0; nc < 4; ++nc) {
        const int c0 = wave * 64 + nc * 16;
        float out[16];
        if constexpr (MODE == MODE_PLAIN) {
#pragma unroll
          for (int j = 0; j < 16; ++j) out[j] = acc[nc][j];
        } else if constexpr (MODE == MODE_BIAS_SSP) {
          float bb[16];
          load16f(bb, bias + c0);
#pragma unroll
          for (int j = 0; j < 16; ++j) out[j] = sspf(acc[nc][j] + bb[j]);
        } else {  // MODE_BIAS_RESID
          float bb[16], rr[16];
          load16f(bb, bias + c0);
          load16a(rr, resid + (size_t)m * HID + c0);
#pragma unroll
          for (int j = 0; j < 16; ++j) out[j] = rr[j] + acc[nc][j] + bb[j];
        }
        store16c(C + (size_t)m * HID + c0, out);
      }
    }
  }
}

// ---------------------------------------------------------------------------
// Fused edge pipeline (geometry recomputed in-kernel):
//   t = ssp(rbf @ W1 + b1); Wf = (t @ W2 + b2)*C; agg[dst] += x1[src]*Wf
// AGGF32: native fp32 atomicAdd; else packed-bf16 CAS.
template <bool AGGF32>
__global__ __launch_bounds__(256) void edge_kernel(
    const int* __restrict__ ei, const float* __restrict__ pos,
    const float* __restrict__ x1, void* __restrict__ aggv,
    const float* __restrict__ W1, const float* __restrict__ b1,
    const float* __restrict__ W2, const float* __restrict__ b2) {
  __shared__ float T[64 * 132];
  __shared__ float rbf[64 * NGAUSS];
  __shared__ float distS[64], cS[64];
  __shared__ int srcS[64], dstS[64];

  const int tid = threadIdx.x;
  const int e0 = blockIdx.x * 64;
  if (tid < 64) {
    int e = e0 + tid;
    int s = ei[e], d = ei[N_EDGES + e];
    srcS[tid] = s;
    dstS[tid] = d;
    float dx = pos[s * 3 + 0] - pos[d * 3 + 0];
    float dy = pos[s * 3 + 1] - pos[d * 3 + 1];
    float dz = pos[s * 3 + 2] - pos[d * 3 + 2];
    float dist = sqrtf(fmaf(dx, dx, fmaf(dy, dy, dz * dz)) + 1e-12f);
    distS[tid] = dist;
    cS[tid] = 0.5f * (cosf(dist * (3.14159265358979323846f / 5.0f)) + 1.0f);
  }
  __syncthreads();

  const float delta = 5.0f / 49.0f;
  const float coeff = -0.5f / (delta * delta);
  for (int i = tid; i < 64 * NGAUSS; i += 256) {
    int e = i / NGAUSS;
    int g = i - e * NGAUSS;
    float dd = distS[e] - (float)g * delta;
    rbf[i] = expf(coeff * dd * dd);
  }

  const int wave = __builtin_amdgcn_readfirstlane(tid >> 6);
  const int lane = tid & 63;
  const float* rrow = &rbf[lane * NGAUSS];

  float acc2[4][16];
#pragma unroll
  for (int nc = 0; nc < 4; ++nc)
#pragma unroll
    for (int j = 0; j < 16; ++j) acc2[nc][j] = 0.0f;

#pragma unroll 1
  for (int half = 0; half < 2; ++half) {
    __syncthreads();  // half0: rbf ready; half1: prior T reads done
#pragma unroll 1
    for (int cc = 0; cc < 2; ++cc) {
      const int c0 = half * 128 + wave * 32 + cc * 16;
      float acc[16];
      load16f(acc, b1 + c0);
#pragma unroll 5
      for (int g = 0; g < NGAUSS; ++g) {
        fma16(acc, rrow[g], W1 + g * HID + c0);
      }
      float* trow = &T[lane * 132 + (c0 - half * 128)];
#pragma unroll
      for (int j = 0; j < 16; ++j) trow[j] = sspf(acc[j]);
    }
    __syncthreads();
    const float4* Trow = (const float4*)&T[lane * 132];
#pragma unroll 2
    for (int k4 = 0; k4 < 32; ++k4) {
      float4 a = Trow[k4];
      const float* Wk = W2 + (half * 128 + k4 * 4) * HID;
#pragma unroll
      for (int nc = 0; nc < 4; ++nc) {
        const float* wp = Wk + wave * 64 + nc * 16;
        fma16(acc2[nc], a.x, wp);
        fma16(acc2[nc], a.y, wp + HID);
        fma16(acc2[nc], a.z, wp + 2 * HID);
        fma16(acc2[nc], a.w, wp + 3 * HID);
      }
    }
  }

  const int s = srcS[lane];
  const int d = dstS[lane];
  const float ce = cS[lane];
#pragma unroll
  for (int nc = 0; nc < 4; ++nc) {
    const int c0 = wave * 64 + nc * 16;
    float bb[16];
    load16f(bb, b2 + c0);
    float xv[16];
    load16f(xv, x1 + (size_t)s * HID + c0);
    if constexpr (AGGF32) {
      float* ar = (float*)aggv + (size_t)d * HID + c0;
#pragma unroll
      for (int j = 0; j < 16; ++j) {
        float wf = (acc2[nc][j] + bb[j]) * ce;
        atomicAdd(ar + j, xv[j] * wf);
      }
    } else {
      uintT* ar = (uintT*)aggv + (size_t)d * (HID / 2) + (c0 >> 1);
#pragma unroll
      for (int jj = 0; jj < 8; ++jj) {
        float wf0 = (acc2[nc][2 * jj] + bb[2 * jj]) * ce;
        float wf1 = (acc2[nc][2 * jj + 1] + bb[2 * jj + 1]) * ce;
        atomic_add_bf16x2(ar + jj, xv[2 * jj] * wf0, xv[2 * jj + 1] * wf1);
      }
    }
  }
}

// ---------------------------------------------------------------------------
__global__ __launch_bounds__(256) void tail_k(const int* __restrict__ batch,
                                              float* __restrict__ out) {
  int i = blockIdx.x * 256 + threadIdx.x;
  if (i < N_NODES) out[i] = (float)batch[i];
}

// ---------------------------------------------------------------------------
extern "C" void kernel_launch(void* const* d_in, const int* in_sizes, int n_in,
                              void* d_out, int out_size, void* d_ws, size_t ws_size,
                              hipStream_t stream) {
  const int* z = (const int*)d_in[0];
  const float* pos = (const float*)d_in[1];
  const int* batch = (const int*)d_in[2];
  const int* ei = (const int*)d_in[3];
  const float* emb = (const float*)d_in[4];
  const float* mlp_w1 = (const float*)d_in[5];
  const float* mlp_b1 = (const float*)d_in[6];
  const float* mlp_w2 = (const float*)d_in[7];
  const float* mlp_b2 = (const float*)d_in[8];
  const float* lin2_w = (const float*)d_in[10];
  const float* lin1_w = (const float*)d_in[9];
  const float* lin2_b = (const float*)d_in[11];
  const float* lin_w = (const float*)d_in[12];
  const float* lin_b = (const float*)d_in[13];
  const float* proj_w = (const float*)d_in[14];
  const float* proj_b = (const float*)d_in[15];
  const float* ln_g = (const float*)d_in[16];
  const float* ln_b = (const float*)d_in[17];
  float* out = (float*)d_out;  // float32: p [N*256] then batch [N]

  const size_t NH = (size_t)N_NODES * HID;
  const int MB = (N_NODES + 63) / 64;
  const bool primary = ws_size >= 3 * NH * sizeof(float);

  if (primary) {
    // all-fp32 scratch: h | x1 | agg  (307.2 MB)
    float* h = (float*)d_ws;
    float* x1 = h + NH;
    float* agg = x1 + NH;

    embed_k<float><<<(N_NODES * HID + 255) / 256, 256, 0, stream>>>(z, emb, h);
    for (int l = 0; l < NLAYERS; ++l) {
      const size_t o2 = (size_t)l * HID * HID;
      const size_t o1 = (size_t)l * HID;
      gemm256<MODE_PLAIN, float, float><<<MB, 256, 0, stream>>>(
          h, lin1_w + o2, nullptr, nullptr, x1, nullptr, N_NODES, nullptr, nullptr);
      hipMemsetAsync(agg, 0, NH * sizeof(float), stream);
      edge_kernel<true><<<N_EDGES / 64, 256, 0, stream>>>(
          ei, pos, x1, agg, mlp_w1 + (size_t)l * NGAUSS * HID, mlp_b1 + o1,
          mlp_w2 + o2, mlp_b2 + o1);
      gemm256<MODE_BIAS_SSP, float, float><<<MB, 256, 0, stream>>>(
          agg, lin2_w + o2, lin2_b + o1, nullptr, x1, nullptr, N_NODES, nullptr, nullptr);
      gemm256<MODE_BIAS_RESID, float, float><<<MB, 256, 0, stream>>>(
          x1, lin_w + o2, lin_b + o1, h, h, nullptr, N_NODES, nullptr, nullptr);
    }
    gemm256<MODE_PROJ_LN, float, float><<<MB, 256, 0, stream>>>(
        h, proj_w, proj_b, nullptr, nullptr, out, N_NODES, ln_g, ln_b);
  } else {
    // compact scratch: h bf16 | agg packed-bf16 in ws (102.4 MB);
    // x1 fp32 scratch inside d_out's p region (overwritten by PROJ_LN).
    ushortT* h = (ushortT*)d_ws;
    uintT* agg2 = (uintT*)((char*)d_ws + NH * sizeof(ushortT));
    float* x1 = out;

    embed_k<ushortT><<<(N_NODES * HID + 255) / 256, 256, 0, stream>>>(z, emb, h);
    for (int l = 0; l < NLAYERS; ++l) {
      const size_t o2 = (size_t)l * HID * HID;
      const size_t o1 = (size_t)l * HID;
      gemm256<MODE_PLAIN, ushortT, float><<<MB, 256, 0, stream>>>(
          h, lin1_w + o2, nullptr, nullptr, x1, nullptr, N_NODES, nullptr, nullptr);
      hipMemsetAsync(agg2, 0, NH * sizeof(ushortT), stream);
      edge_kernel<false><<<N_EDGES / 64, 256, 0, stream>>>(
          ei, pos, x1, agg2, mlp_w1 + (size_t)l * NGAUSS * HID, mlp_b1 + o1,
          mlp_w2 + o2, mlp_b2 + o1);
      gemm256<MODE_BIAS_SSP, ushortT, float><<<MB, 256, 0, stream>>>(
          (const ushortT*)agg2, lin2_w + o2, lin2_b + o1, nullptr, x1, nullptr,
          N_NODES, nullptr, nullptr);
      gemm256<MODE_BIAS_RESID, float, ushortT><<<MB, 256, 0, stream>>>(
          x1, lin_w + o2, lin_b + o1, h, h, nullptr, N_NODES, nullptr, nullptr);
    }
    gemm256<MODE_PROJ_LN, ushortT, float><<<MB, 256, 0, stream>>>(
        h, proj_w, proj_b, nullptr, nullptr, out, N_NODES, ln_g, ln_b);
  }
  tail_k<<<(N_NODES + 255) / 256, 256, 0, stream>>>(batch, out + NH);
}

// Round 4
// 5642.316 us; speedup vs baseline: 5.9667x; 5.9667x over previous
//
#include <hip/hip_runtime.h>

#define N_NODES 100000
#define N_EDGES 320000
#define HID 256
#define NGAUSS 50
#define NLAYERS 6

typedef unsigned short ushortT;
typedef unsigned int uintT;
typedef __attribute__((ext_vector_type(8))) short bf16x8;  // 8 bf16 = 4 VGPR
typedef __attribute__((ext_vector_type(4))) float f32x4;

enum { MODE_PLAIN = 0, MODE_BIAS_SSP = 1, MODE_BIAS_RESID = 2, MODE_PROJ = 3 };

// ---------------------------------------------------------------------------
__device__ __forceinline__ float sspf(float x) {
  return fmaxf(x, 0.0f) + log1pf(expf(-fabsf(x))) - 0.69314718055994530942f;
}

__device__ __forceinline__ float bf2f(ushortT u) {
  union { uintT i; float f; } c;
  c.i = ((uintT)u) << 16;
  return c.f;
}

__device__ __forceinline__ ushortT f2bf(float f) {
  union { float f; uintT i; } c;
  c.f = f;
  uintT i = c.i;
  uintT r = i + 0x7FFFu + ((i >> 16) & 1u);  // RNE
  return (ushortT)(r >> 16);
}

__device__ __forceinline__ void load16f(float (&b)[16], const float* __restrict__ p) {
  const float4 v0 = *(const float4*)(p + 0);
  const float4 v1 = *(const float4*)(p + 4);
  const float4 v2 = *(const float4*)(p + 8);
  const float4 v3 = *(const float4*)(p + 12);
  b[0] = v0.x;  b[1] = v0.y;  b[2] = v0.z;  b[3] = v0.w;
  b[4] = v1.x;  b[5] = v1.y;  b[6] = v1.z;  b[7] = v1.w;
  b[8] = v2.x;  b[9] = v2.y;  b[10] = v2.z; b[11] = v2.w;
  b[12] = v3.x; b[13] = v3.y; b[14] = v3.z; b[15] = v3.w;
}

// store 16 floats as bf16 (works for LDS or global pointers)
__device__ __forceinline__ void store16bf(ushortT* p, const float (&v)[16]) {
  uint4 u0, u1;
  u0.x = (uintT)f2bf(v[0])  | ((uintT)f2bf(v[1])  << 16);
  u0.y = (uintT)f2bf(v[2])  | ((uintT)f2bf(v[3])  << 16);
  u0.z = (uintT)f2bf(v[4])  | ((uintT)f2bf(v[5])  << 16);
  u0.w = (uintT)f2bf(v[6])  | ((uintT)f2bf(v[7])  << 16);
  u1.x = (uintT)f2bf(v[8])  | ((uintT)f2bf(v[9])  << 16);
  u1.y = (uintT)f2bf(v[10]) | ((uintT)f2bf(v[11]) << 16);
  u1.z = (uintT)f2bf(v[12]) | ((uintT)f2bf(v[13]) << 16);
  u1.w = (uintT)f2bf(v[14]) | ((uintT)f2bf(v[15]) << 16);
  *(uint4*)(p + 0) = u0;
  *(uint4*)(p + 8) = u1;
}

// acc[j] += a * w[j]; w wave-uniform fp32 weights -> scalar loads
__device__ __forceinline__ void fma16(float (&ac)[16], const float a, const float* __restrict__ w) {
  const float4 w0 = *(const float4*)(w + 0);
  const float4 w1 = *(const float4*)(w + 4);
  const float4 w2 = *(const float4*)(w + 8);
  const float4 w3 = *(const float4*)(w + 12);
  ac[0]  = fmaf(a, w0.x, ac[0]);  ac[1]  = fmaf(a, w0.y, ac[1]);
  ac[2]  = fmaf(a, w0.z, ac[2]);  ac[3]  = fmaf(a, w0.w, ac[3]);
  ac[4]  = fmaf(a, w1.x, ac[4]);  ac[5]  = fmaf(a, w1.y, ac[5]);
  ac[6]  = fmaf(a, w1.z, ac[6]);  ac[7]  = fmaf(a, w1.w, ac[7]);
  ac[8]  = fmaf(a, w2.x, ac[8]);  ac[9]  = fmaf(a, w2.y, ac[9]);
  ac[10] = fmaf(a, w2.z, ac[10]); ac[11] = fmaf(a, w2.w, ac[11]);
  ac[12] = fmaf(a, w3.x, ac[12]); ac[13] = fmaf(a, w3.y, ac[13]);
  ac[14] = fmaf(a, w3.z, ac[14]); ac[15] = fmaf(a, w3.w, ac[15]);
}

// ---------------------------------------------------------------------------
// Shared MFMA K-loop: acc[rt][ct] += A_lds[64x256] @ Bt_global[64-col stripe].
// A in LDS, bf16, row stride 264 elements. Bt row-major [N,K] bf16 (pre-transposed
// weights), stripe base passed in. Layouts (guide, m89/m121-verified):
//   A-frag: lane(16q+m) holds A[m][8q..8q+8); B-frag: lane(16q+n) holds B[8q..][n]
//   C/D:    lane(16q+c) reg r -> (row=4q+r, col=c) within the 16x16 tile.
__device__ __forceinline__ void mfma_kloop(const ushortT* As, const ushortT* Bt,
                                           f32x4 (&acc)[4][4], int lm, int q) {
#pragma unroll
  for (int k = 0; k < 256; k += 32) {
    bf16x8 a[4], b[4];
#pragma unroll
    for (int rt = 0; rt < 4; ++rt)
      a[rt] = *(const bf16x8*)&As[(rt * 16 + lm) * 264 + k + 8 * q];
#pragma unroll
    for (int ct = 0; ct < 4; ++ct)
      b[ct] = *(const bf16x8*)(Bt + (size_t)(ct * 16 + lm) * HID + k + 8 * q);
#pragma unroll
    for (int rt = 0; rt < 4; ++rt)
#pragma unroll
      for (int ct = 0; ct < 4; ++ct)
        acc[rt][ct] = __builtin_amdgcn_mfma_f32_16x16x32_bf16(a[rt], b[ct], acc[rt][ct], 0, 0, 0);
  }
}

// ---------------------------------------------------------------------------
// MFMA node GEMM: C[M,256] = f(A[M,256] @ W[256,256] [+bias] [+resid])
// A bf16, Bt = bf16 transposed weights [N,K]. Block: 64 rows, wave w -> cols 64w..64w+64.
template <int MODE>
__global__ __launch_bounds__(256) void mgemm(const ushortT* __restrict__ A,
                                             const ushortT* __restrict__ Bt,
                                             const float* __restrict__ bias,
                                             ushortT* __restrict__ Cbf,
                                             float* __restrict__ Cf, int M) {
  __shared__ ushortT As[64 * 264];  // 33792 B, padded stride vs LDS banks
  const int tid = threadIdx.x;
  const int m0 = blockIdx.x * 64;

  // stage A rows m0..m0+63 (512B each) via 16B loads/stores
#pragma unroll
  for (int i = 0; i < 8; ++i) {
    int idx = i * 256 + tid;         // [0,2048)
    int r = idx >> 5, ch = idx & 31; // row, 8-bf16 chunk
    int m = m0 + r;
    uint4 u = make_uint4(0, 0, 0, 0);
    if (m < M) u = *(const uint4*)(A + (size_t)m * HID + ch * 8);
    *(uint4*)&As[r * 264 + ch * 8] = u;
  }
  __syncthreads();

  const int wave = __builtin_amdgcn_readfirstlane(tid >> 6);
  const int lane = tid & 63;
  const int lm = lane & 15, q = lane >> 4;
  const int c0 = wave * 64;

  f32x4 acc[4][4];
#pragma unroll
  for (int rt = 0; rt < 4; ++rt)
#pragma unroll
    for (int ct = 0; ct < 4; ++ct) acc[rt][ct] = (f32x4){0.f, 0.f, 0.f, 0.f};

  mfma_kloop(As, Bt + (size_t)c0 * HID, acc, lm, q);

#pragma unroll
  for (int ct = 0; ct < 4; ++ct) {
    const int col = c0 + ct * 16 + lm;
    float bv = 0.0f;
    if constexpr (MODE != MODE_PLAIN) bv = bias[col];
#pragma unroll
    for (int rt = 0; rt < 4; ++rt) {
#pragma unroll
      for (int r = 0; r < 4; ++r) {
        int m = m0 + rt * 16 + q * 4 + r;
        if (m < M) {
          float v = acc[rt][ct][r] + bv;
          if constexpr (MODE == MODE_BIAS_SSP) v = sspf(v);
          if constexpr (MODE == MODE_BIAS_RESID) v += bf2f(Cbf[(size_t)m * HID + col]);
          if constexpr (MODE == MODE_PROJ) Cf[(size_t)m * HID + col] = v;
          else Cbf[(size_t)m * HID + col] = f2bf(v);
        }
      }
    }
  }
}

// ---------------------------------------------------------------------------
// Edge kernel: per 64 edges, compute t = ssp(rbf@W1+b1) (scalar fp32, wave-uniform
// weight loads), then Wf = t@W2t via MFMA, then msg[e] = x1[src]*(Wf+b2)*C(dist).
// No atomics — msg is materialized, gather_k segment-sums it.
__global__ __launch_bounds__(256) void edge_mfma(
    const int* __restrict__ ei, const float* __restrict__ pos,
    const ushortT* __restrict__ x1, ushortT* __restrict__ msg,
    const float* __restrict__ W1, const float* __restrict__ b1,
    const ushortT* __restrict__ W2t, const float* __restrict__ b2) {
  __shared__ ushortT T[64 * 264];     // 33792 B (bf16 t-matrix, MFMA A-layout)
  __shared__ float rbf[64 * 51];      // stride 51 (odd) -> conflict-free
  __shared__ float cS[64];
  __shared__ int srcS[64];

  const int tid = threadIdx.x;
  const int e0 = blockIdx.x * 64;
  if (tid < 64) {
    int e = e0 + tid;
    int s = ei[e], d = ei[N_EDGES + e];
    srcS[tid] = s;
    float dx = pos[s * 3 + 0] - pos[d * 3 + 0];
    float dy = pos[s * 3 + 1] - pos[d * 3 + 1];
    float dz = pos[s * 3 + 2] - pos[d * 3 + 2];
    float dist = sqrtf(fmaf(dx, dx, fmaf(dy, dy, dz * dz)) + 1e-12f);
    rbf[64 * 50 + tid] = dist;  // stash dist in rbf tail pad? no — use cS path below
    cS[tid] = 0.5f * (cosf(dist * (3.14159265358979323846f / 5.0f)) + 1.0f);
  }
  __syncthreads();

  const float delta = 5.0f / 49.0f;
  const float coeff = -0.5f / (delta * delta);
  for (int i = tid; i < 64 * NGAUSS; i += 256) {
    int e = i / NGAUSS;
    int g = i - e * NGAUSS;
    float dist = rbf[64 * 50 + e];  // read stashed dist (same region, pre-overwrite)
    float dd = dist - (float)g * delta;
    rbf[e * 51 + g] = 0.0f;  // placeholder, overwritten below
    rbf[e * 51 + g] = expf(coeff * dd * dd);
  }
  __syncthreads();

  const int wave = __builtin_amdgcn_readfirstlane(tid >> 6);
  const int lane = tid & 63;
  const float* rrow = &rbf[lane * 51];

  // phase 1: wave w computes t cols [64w, 64w+64) for its lane's edge (scalar fp32)
#pragma unroll 1
  for (int cc = 0; cc < 4; ++cc) {
    const int c0p = wave * 64 + cc * 16;
    float acc1[16];
    load16f(acc1, b1 + c0p);
#pragma unroll 5
    for (int g = 0; g < NGAUSS; ++g) fma16(acc1, rrow[g], W1 + g * HID + c0p);
    float tv[16];
#pragma unroll
    for (int j = 0; j < 16; ++j) tv[j] = sspf(acc1[j]);
    store16bf(&T[lane * 264 + c0p], tv);
  }
  __syncthreads();

  // phase 2: Wf = t @ W2 via MFMA; wave w covers cols [64w, 64w+64)
  const int lm = lane & 15, q = lane >> 4;
  const int c0 = wave * 64;
  f32x4 acc[4][4];
#pragma unroll
  for (int rt = 0; rt < 4; ++rt)
#pragma unroll
    for (int ct = 0; ct < 4; ++ct) acc[rt][ct] = (f32x4){0.f, 0.f, 0.f, 0.f};

  mfma_kloop(T, W2t + (size_t)c0 * HID, acc, lm, q);

  // epilogue: msg[e][col] = x1[src[e]][col] * (Wf + b2[col]) * C(e)
#pragma unroll
  for (int ct = 0; ct < 4; ++ct) {
    const int col = c0 + ct * 16 + lm;
    const float bv = b2[col];
#pragma unroll
    for (int rt = 0; rt < 4; ++rt) {
#pragma unroll
      for (int r = 0; r < 4; ++r) {
        int row = rt * 16 + q * 4 + r;
        float wf = (acc[rt][ct][r] + bv) * cS[row];
        float xv = bf2f(x1[(size_t)srcS[row] * HID + col]);
        msg[(size_t)(e0 + row) * HID + col] = f2bf(wf * xv);
      }
    }
  }
}

// ---------------------------------------------------------------------------
// CSR build: histogram -> single-block scan -> scatter edge ids
__global__ __launch_bounds__(256) void hist_k(const int* __restrict__ ei,
                                              int* __restrict__ counts) {
  int e = blockIdx.x * 256 + threadIdx.x;
  if (e < N_EDGES) atomicAdd(&counts[ei[N_EDGES + e]], 1);
}

__global__ __launch_bounds__(256) void scan_k(const int* __restrict__ counts,
                                              int* __restrict__ row_start,
                                              int* __restrict__ cursor) {
  __shared__ int sums[256];
  const int tid = threadIdx.x;
  const int CH = (N_NODES + 255) / 256;  // 391
  const int base = tid * CH;
  int s = 0;
  for (int i = 0; i < CH; ++i) {
    int n = base + i;
    if (n < N_NODES) s += counts[n];
  }
  sums[tid] = s;
  __syncthreads();
  if (tid == 0) {
    int acc = 0;
    for (int i = 0; i < 256; ++i) { int t = sums[i]; sums[i] = acc; acc += t; }
  }
  __syncthreads();
  int off = sums[tid];
  for (int i = 0; i < CH; ++i) {
    int n = base + i;
    if (n < N_NODES) {
      row_start[n] = off;
      cursor[n] = off;
      off += counts[n];
    }
  }
  if (tid == 255) row_start[N_NODES] = off;
}

__global__ __launch_bounds__(256) void scatter_k(const int* __restrict__ ei,
                                                 int* __restrict__ cursor,
                                                 int* __restrict__ eo) {
  int e = blockIdx.x * 256 + threadIdx.x;
  if (e < N_EDGES) {
    int p = atomicAdd(&cursor[ei[N_EDGES + e]], 1);
    eo[p] = e;
  }
}

// gather: agg[d] = sum over msg rows of d's incoming edges. 1 wave per node.
__global__ __launch_bounds__(256) void gather_k(const int* __restrict__ row_start,
                                                const int* __restrict__ eo,
                                                const ushortT* __restrict__ msg,
                                                ushortT* __restrict__ agg) {
  int node = blockIdx.x * 4 + (threadIdx.x >> 6);
  int lane = threadIdx.x & 63;
  if (node >= N_NODES) return;
  int a = row_start[node], b = row_start[node + 1];
  float s0 = 0.f, s1 = 0.f, s2 = 0.f, s3 = 0.f;
  for (int j = a; j < b; ++j) {
    int e = eo[j];
    uint2 u = *(const uint2*)(msg + (size_t)e * HID + lane * 4);
    s0 += bf2f(u.x & 0xFFFF); s1 += bf2f(u.x >> 16);
    s2 += bf2f(u.y & 0xFFFF); s3 += bf2f(u.y >> 16);
  }
  uint2 o;
  o.x = (uintT)f2bf(s0) | ((uintT)f2bf(s1) << 16);
  o.y = (uintT)f2bf(s2) | ((uintT)f2bf(s3) << 16);
  *(uint2*)(agg + (size_t)node * HID + lane * 4) = o;
}

// ---------------------------------------------------------------------------
// Weight prep: fp32 W[K,256] -> bf16 Wt[256,K] per matrix; grid = nmat*16 tiles
__global__ __launch_bounds__(256) void wconv_k(const float* __restrict__ src,
                                               ushortT* __restrict__ dst) {
  __shared__ float tile[64][65];
  const int b = blockIdx.x;
  const int mat = b >> 4, t = b & 15;
  const int tr = (t >> 2) * 64, tc = (t & 3) * 64;  // k-origin, n-origin
  const float* S = src + (size_t)mat * HID * HID;
  ushortT* D = dst + (size_t)mat * HID * HID;
  const int tid = threadIdx.x;
#pragma unroll
  for (int i = 0; i < 16; ++i) {
    int idx = i * 256 + tid;
    int r = idx >> 6, c = idx & 63;
    tile[r][c] = S[(size_t)(tr + r) * HID + tc + c];
  }
  __syncthreads();
#pragma unroll
  for (int i = 0; i < 16; ++i) {
    int idx = i * 256 + tid;
    int n = idx >> 6, k = idx & 63;
    D[(size_t)(tc + n) * HID + tr + k] = f2bf(tile[k][n]);
  }
}

// ---------------------------------------------------------------------------
__global__ __launch_bounds__(256) void embed_k(const int* __restrict__ z,
                                               const float* __restrict__ emb,
                                               ushortT* __restrict__ h) {
  int idx = blockIdx.x * 256 + threadIdx.x;
  if (idx >= N_NODES * HID) return;
  int n = idx >> 8;
  int c = idx & 255;
  h[idx] = f2bf(emb[z[n] * HID + c]);
}

// LayerNorm + SiLU on p (fp32), write final float32 output
__global__ __launch_bounds__(256) void ln_k(const float* __restrict__ p,
                                            const float* __restrict__ g,
                                            const float* __restrict__ b,
                                            float* __restrict__ out) {
  const int row = blockIdx.x;
  const int tid = threadIdx.x;
  const int wave = tid >> 6, lane = tid & 63;
  __shared__ float red[4], red2[4];

  float v = p[(size_t)row * HID + tid];
  float s = v;
#pragma unroll
  for (int m = 32; m; m >>= 1) s += __shfl_xor(s, m, 64);
  if (lane == 0) red[wave] = s;
  __syncthreads();
  float mu = (red[0] + red[1] + red[2] + red[3]) * (1.0f / 256.0f);
  float diff = v - mu;
  float qv = diff * diff;
#pragma unroll
  for (int m = 32; m; m >>= 1) qv += __shfl_xor(qv, m, 64);
  if (lane == 0) red2[wave] = qv;
  __syncthreads();
  float var = (red2[0] + red2[1] + red2[2] + red2[3]) * (1.0f / 256.0f);
  float y = diff * rsqrtf(var + 1e-5f) * g[tid] + b[tid];
  out[(size_t)row * HID + tid] = y * (1.0f / (1.0f + expf(-y)));
}

__global__ __launch_bounds__(256) void tail_k(const int* __restrict__ batch,
                                              float* __restrict__ out) {
  int i = blockIdx.x * 256 + threadIdx.x;
  if (i < N_NODES) out[i] = (float)batch[i];
}

// ---------------------------------------------------------------------------
extern "C" void kernel_launch(void* const* d_in, const int* in_sizes, int n_in,
                              void* d_out, int out_size, void* d_ws, size_t ws_size,
                              hipStream_t stream) {
  const int* z = (const int*)d_in[0];
  const float* pos = (const float*)d_in[1];
  const int* batch = (const int*)d_in[2];
  const int* ei = (const int*)d_in[3];
  const float* emb = (const float*)d_in[4];
  const float* mlp_w1 = (const float*)d_in[5];
  const float* mlp_b1 = (const float*)d_in[6];
  const float* mlp_w2 = (const float*)d_in[7];
  const float* mlp_b2 = (const float*)d_in[8];
  const float* lin1_w = (const float*)d_in[9];
  const float* lin2_w = (const float*)d_in[10];
  const float* lin2_b = (const float*)d_in[11];
  const float* lin_w = (const float*)d_in[12];
  const float* lin_b = (const float*)d_in[13];
  const float* proj_w = (const float*)d_in[14];
  const float* proj_b = (const float*)d_in[15];
  const float* ln_g = (const float*)d_in[16];
  const float* ln_b = (const float*)d_in[17];
  float* out = (float*)d_out;  // fp32: p [N*256] then batch [N]

  const size_t NH = (size_t)N_NODES * HID;
  const size_t EH = (size_t)N_EDGES * HID;
  const size_t WSZ = (size_t)HID * HID;  // 65536 elems per matrix

  // ---- workspace layout (~322 MB) ----
  char* w = (char*)d_ws;
  ushortT* h = (ushortT*)w;      w += NH * 2;
  ushortT* x1 = (ushortT*)w;     w += NH * 2;     // also holds t = ssp(...)
  ushortT* agg = (ushortT*)w;    w += NH * 2;
  ushortT* msg = (ushortT*)w;                     // [E,H] bf16
  float* p = (float*)msg;                         // proj output aliases msg
  w += EH * 2;
  ushortT* lin1t = (ushortT*)w;  w += 6 * WSZ * 2;
  ushortT* lin2t = (ushortT*)w;  w += 6 * WSZ * 2;
  ushortT* lint = (ushortT*)w;   w += 6 * WSZ * 2;
  ushortT* w2t = (ushortT*)w;    w += 6 * WSZ * 2;
  ushortT* projt = (ushortT*)w;  w += WSZ * 2;
  int* counts = (int*)w;         w += (size_t)N_NODES * 4;
  int* cursor = (int*)w;         w += (size_t)N_NODES * 4;
  int* row_start = (int*)w;      w += (size_t)(N_NODES + 64) * 4;
  int* eo = (int*)w;             w += (size_t)N_EDGES * 4;

  // ---- CSR build (same every call; edge_index is fixed input) ----
  hipMemsetAsync(counts, 0, (size_t)N_NODES * 4, stream);
  hist_k<<<(N_EDGES + 255) / 256, 256, 0, stream>>>(ei, counts);
  scan_k<<<1, 256, 0, stream>>>(counts, row_start, cursor);
  scatter_k<<<(N_EDGES + 255) / 256, 256, 0, stream>>>(ei, cursor, eo);

  // ---- weight convert + transpose to bf16 [N,K] ----
  wconv_k<<<6 * 16, 256, 0, stream>>>(lin1_w, lin1t);
  wconv_k<<<6 * 16, 256, 0, stream>>>(lin2_w, lin2t);
  wconv_k<<<6 * 16, 256, 0, stream>>>(lin_w, lint);
  wconv_k<<<6 * 16, 256, 0, stream>>>(mlp_w2, w2t);
  wconv_k<<<16, 256, 0, stream>>>(proj_w, projt);

  embed_k<<<(N_NODES * HID + 255) / 256, 256, 0, stream>>>(z, emb, h);

  const int MB = (N_NODES + 63) / 64;
  for (int l = 0; l < NLAYERS; ++l) {
    const size_t oW = (size_t)l * WSZ;
    const size_t o1 = (size_t)l * HID;
    // x1 = h @ lin1
    mgemm<MODE_PLAIN><<<MB, 256, 0, stream>>>(h, lin1t + oW, nullptr, x1, nullptr, N_NODES);
    // msg[e] = x1[src]*Wf  (fused filter MLP, MFMA phase 2)
    edge_mfma<<<N_EDGES / 64, 256, 0, stream>>>(ei, pos, x1, msg,
                                                mlp_w1 + (size_t)l * NGAUSS * HID,
                                                mlp_b1 + o1, w2t + oW, mlp_b2 + o1);
    // agg = segment_sum(msg, dst)
    gather_k<<<(N_NODES + 3) / 4, 256, 0, stream>>>(row_start, eo, msg, agg);
    // t = ssp(agg @ lin2 + b2)  -> x1
    mgemm<MODE_BIAS_SSP><<<MB, 256, 0, stream>>>(agg, lin2t + oW, lin2_b + o1, x1, nullptr, N_NODES);
    // h = h + (t @ lin + b)
    mgemm<MODE_BIAS_RESID><<<MB, 256, 0, stream>>>(x1, lint + oW, lin_b + o1, h, nullptr, N_NODES);
  }
  // p = h @ proj_w + proj_b (fp32, into msg region)
  mgemm<MODE_PROJ><<<MB, 256, 0, stream>>>(h, projt, proj_b, nullptr, p, N_NODES);
  ln_k<<<N_NODES, 256, 0, stream>>>(p, ln_g, ln_b, out);
  tail_k<<<(N_NODES + 255) / 256, 256, 0, stream>>>(batch, out + NH);
}

// Round 5
// 4341.825 us; speedup vs baseline: 7.7539x; 1.2995x over previous
//
#include <hip/hip_runtime.h>

#define N_NODES 100000
#define N_EDGES 320000
#define HID 256
#define NGAUSS 50
#define NLAYERS 6

typedef unsigned short ushortT;
typedef unsigned int uintT;
typedef __attribute__((ext_vector_type(8))) short bf16x8;  // 8 bf16 = 4 VGPR
typedef __attribute__((ext_vector_type(4))) float f32x4;

enum { MODE_PLAIN = 0, MODE_BIAS_SSP = 1, MODE_BIAS_RESID = 2, MODE_PROJ = 3 };

// ---------------------------------------------------------------------------
__device__ __forceinline__ float sspf(float x) {
  return fmaxf(x, 0.0f) + log1pf(expf(-fabsf(x))) - 0.69314718055994530942f;
}

__device__ __forceinline__ float bf2f(ushortT u) {
  union { uintT i; float f; } c;
  c.i = ((uintT)u) << 16;
  return c.f;
}

__device__ __forceinline__ ushortT f2bf(float f) {
  union { float f; uintT i; } c;
  c.f = f;
  uintT i = c.i;
  uintT r = i + 0x7FFFu + ((i >> 16) & 1u);  // RNE
  return (ushortT)(r >> 16);
}

// ---------------------------------------------------------------------------
// Shared MFMA K-loop over K=256: acc[rt][ct] += A_lds[64x256] @ Bt[64-col stripe]
// A in LDS bf16 (row stride 264), Bt row-major [N,K] bf16. Layouts (verified):
//   A-frag: lane(16q+m) holds A[m][8q..8q+8); C/D: lane(16q+c) reg r -> row 4q+r, col c
__device__ __forceinline__ void mfma_kloop(const ushortT* As, const ushortT* Bt,
                                           f32x4 (&acc)[4][4], int lm, int q) {
#pragma unroll
  for (int k = 0; k < 256; k += 32) {
    bf16x8 a[4], b[4];
#pragma unroll
    for (int rt = 0; rt < 4; ++rt)
      a[rt] = *(const bf16x8*)&As[(rt * 16 + lm) * 264 + k + 8 * q];
#pragma unroll
    for (int ct = 0; ct < 4; ++ct)
      b[ct] = *(const bf16x8*)(Bt + (size_t)(ct * 16 + lm) * HID + k + 8 * q);
#pragma unroll
    for (int rt = 0; rt < 4; ++rt)
#pragma unroll
      for (int ct = 0; ct < 4; ++ct)
        acc[rt][ct] = __builtin_amdgcn_mfma_f32_16x16x32_bf16(a[rt], b[ct], acc[rt][ct], 0, 0, 0);
  }
}

// ---------------------------------------------------------------------------
// MFMA node GEMM: C[M,256] = f(A[M,256] @ W[256,256] [+bias] [+resid])
template <int MODE>
__global__ __launch_bounds__(256) void mgemm(const ushortT* __restrict__ A,
                                             const ushortT* __restrict__ Bt,
                                             const float* __restrict__ bias,
                                             ushortT* __restrict__ Cbf,
                                             float* __restrict__ Cf, int M) {
  __shared__ ushortT As[64 * 264];
  const int tid = threadIdx.x;
  const int m0 = blockIdx.x * 64;

#pragma unroll
  for (int i = 0; i < 8; ++i) {
    int idx = i * 256 + tid;
    int r = idx >> 5, ch = idx & 31;
    int m = m0 + r;
    uint4 u = make_uint4(0, 0, 0, 0);
    if (m < M) u = *(const uint4*)(A + (size_t)m * HID + ch * 8);
    *(uint4*)&As[r * 264 + ch * 8] = u;
  }
  __syncthreads();

  const int wave = __builtin_amdgcn_readfirstlane(tid >> 6);
  const int lane = tid & 63;
  const int lm = lane & 15, q = lane >> 4;
  const int c0 = wave * 64;

  f32x4 acc[4][4];
#pragma unroll
  for (int rt = 0; rt < 4; ++rt)
#pragma unroll
    for (int ct = 0; ct < 4; ++ct) acc[rt][ct] = (f32x4){0.f, 0.f, 0.f, 0.f};

  mfma_kloop(As, Bt + (size_t)c0 * HID, acc, lm, q);

#pragma unroll
  for (int ct = 0; ct < 4; ++ct) {
    const int col = c0 + ct * 16 + lm;
    float bv = 0.0f;
    if constexpr (MODE != MODE_PLAIN) bv = bias[col];
#pragma unroll
    for (int rt = 0; rt < 4; ++rt) {
#pragma unroll
      for (int r = 0; r < 4; ++r) {
        int m = m0 + rt * 16 + q * 4 + r;
        if (m < M) {
          float v = acc[rt][ct][r] + bv;
          if constexpr (MODE == MODE_BIAS_SSP) v = sspf(v);
          if constexpr (MODE == MODE_BIAS_RESID) v += bf2f(Cbf[(size_t)m * HID + col]);
          if constexpr (MODE == MODE_PROJ) Cf[(size_t)m * HID + col] = v;
          else Cbf[(size_t)m * HID + col] = f2bf(v);
        }
      }
    }
  }
}

// ---------------------------------------------------------------------------
// Edge kernel, all-MFMA: per 64 edges,
//   R = rbf(dist) bf16 [64 x 64pad]   (in-kernel expf, LDS)
//   t = ssp(R @ w1t + b1)             (MFMA, 32 mfma)  -> T (LDS, A-layout)
//   Wf = t @ w2t + b2                 (MFMA, 128 mfma) -> T (reused, after sync)
//   msg[perm[e]] = x1[src] * Wf * C(dist)   (vectorized row pass)
__global__ __launch_bounds__(256) void edge_mfma(
    const int* __restrict__ ei, const float* __restrict__ pos,
    const int* __restrict__ perm, const ushortT* __restrict__ x1,
    ushortT* __restrict__ msg,
    const ushortT* __restrict__ w1t,  // bf16 [256][64], k padded 50->64
    const float* __restrict__ b1,
    const ushortT* __restrict__ w2t,  // bf16 [256][256]
    const float* __restrict__ b2) {
  __shared__ ushortT T[64 * 264];   // 33792 B
  __shared__ ushortT R[64 * 72];    // 9216 B, rbf A-tile, stride 72
  __shared__ float cS[64], distS[64];
  __shared__ int srcS[64], permS[64];

  const int tid = threadIdx.x;
  const int e0 = blockIdx.x * 64;
  if (tid < 64) {
    int e = e0 + tid;
    int s = ei[e], d = ei[N_EDGES + e];
    srcS[tid] = s;
    permS[tid] = perm[e];
    float dx = pos[s * 3 + 0] - pos[d * 3 + 0];
    float dy = pos[s * 3 + 1] - pos[d * 3 + 1];
    float dz = pos[s * 3 + 2] - pos[d * 3 + 2];
    float dist = sqrtf(fmaf(dx, dx, fmaf(dy, dy, dz * dz)) + 1e-12f);
    distS[tid] = dist;
    cS[tid] = 0.5f * (cosf(dist * (3.14159265358979323846f / 5.0f)) + 1.0f);
  }
  __syncthreads();

  // rbf fill (bf16, zero-padded k=50..63): 16 expf per thread
  const float delta = 5.0f / 49.0f;
  const float coeff = -0.5f / (delta * delta);
#pragma unroll
  for (int i = 0; i < 16; ++i) {
    int idx = i * 256 + tid;        // [0,4096)
    int e = idx >> 6, k = idx & 63;
    float v = 0.0f;
    if (k < NGAUSS) {
      float dd = distS[e] - (float)k * delta;
      v = expf(coeff * dd * dd);
    }
    R[e * 72 + k] = f2bf(v);
  }
  __syncthreads();

  const int wave = __builtin_amdgcn_readfirstlane(tid >> 6);
  const int lane = tid & 63;
  const int lm = lane & 15, q = lane >> 4;
  const int c0 = wave * 64;

  // ---- phase 1: t = ssp(R @ w1t + b1), K=64 (2 mfma k-steps) ----
  {
    f32x4 acc1[4][4];
#pragma unroll
    for (int rt = 0; rt < 4; ++rt)
#pragma unroll
      for (int ct = 0; ct < 4; ++ct) acc1[rt][ct] = (f32x4){0.f, 0.f, 0.f, 0.f};
#pragma unroll
    for (int k = 0; k < 64; k += 32) {
      bf16x8 a[4], b[4];
#pragma unroll
      for (int rt = 0; rt < 4; ++rt)
        a[rt] = *(const bf16x8*)&R[(rt * 16 + lm) * 72 + k + 8 * q];
#pragma unroll
      for (int ct = 0; ct < 4; ++ct)
        b[ct] = *(const bf16x8*)(w1t + (size_t)(c0 + ct * 16 + lm) * 64 + k + 8 * q);
#pragma unroll
      for (int rt = 0; rt < 4; ++rt)
#pragma unroll
        for (int ct = 0; ct < 4; ++ct)
          acc1[rt][ct] = __builtin_amdgcn_mfma_f32_16x16x32_bf16(a[rt], b[ct], acc1[rt][ct], 0, 0, 0);
    }
#pragma unroll
    for (int ct = 0; ct < 4; ++ct) {
      const int col = c0 + ct * 16 + lm;
      const float bv = b1[col];
#pragma unroll
      for (int rt = 0; rt < 4; ++rt)
#pragma unroll
        for (int r = 0; r < 4; ++r) {
          int row = rt * 16 + q * 4 + r;
          T[row * 264 + col] = f2bf(sspf(acc1[rt][ct][r] + bv));
        }
    }
  }
  __syncthreads();

  // ---- phase 2: Wf = t @ w2t + b2, K=256 ----
  f32x4 acc[4][4];
#pragma unroll
  for (int rt = 0; rt < 4; ++rt)
#pragma unroll
    for (int ct = 0; ct < 4; ++ct) acc[rt][ct] = (f32x4){0.f, 0.f, 0.f, 0.f};
  mfma_kloop(T, w2t + (size_t)c0 * HID, acc, lm, q);
  __syncthreads();  // all waves done reading T -> safe to overwrite

#pragma unroll
  for (int ct = 0; ct < 4; ++ct) {
    const int col = c0 + ct * 16 + lm;
    const float bv = b2[col];
#pragma unroll
    for (int rt = 0; rt < 4; ++rt)
#pragma unroll
      for (int r = 0; r < 4; ++r) {
        int row = rt * 16 + q * 4 + r;
        T[row * 264 + col] = f2bf(acc[rt][ct][r] + bv);
      }
  }
  __syncthreads();

  // ---- vectorized msg pass: 4 threads per row, 8 bf16 per chunk ----
  {
    const int row = tid >> 2, sub = tid & 3;
    const int src = srcS[row];
    const int pm = permS[row];
    const float cs = cS[row];
    const ushortT* xrow = x1 + (size_t)src * HID;
    ushortT* mrow = msg + (size_t)pm * HID;
#pragma unroll
    for (int c8 = 0; c8 < 8; ++c8) {
      const int col = c8 * 32 + sub * 8;  // quad covers 32 consecutive cols
      const uint4 tw = *(const uint4*)&T[row * 264 + col];
      const uint4 xw = *(const uint4*)(xrow + col);
      uint4 o;
      const uintT tws[4] = {tw.x, tw.y, tw.z, tw.w};
      const uintT xws[4] = {xw.x, xw.y, xw.z, xw.w};
      uintT os[4];
#pragma unroll
      for (int j = 0; j < 4; ++j) {
        float lo = bf2f(tws[j] & 0xFFFF) * bf2f(xws[j] & 0xFFFF) * cs;
        float hi = bf2f(tws[j] >> 16) * bf2f(xws[j] >> 16) * cs;
        os[j] = (uintT)f2bf(lo) | ((uintT)f2bf(hi) << 16);
      }
      o.x = os[0]; o.y = os[1]; o.z = os[2]; o.w = os[3];
      *(uint4*)(mrow + col) = o;
    }
  }
}

// ---------------------------------------------------------------------------
// CSR build: histogram -> single-block scan -> perm (edge -> CSR slot)
__global__ __launch_bounds__(256) void hist_k(const int* __restrict__ ei,
                                              int* __restrict__ counts) {
  int e = blockIdx.x * 256 + threadIdx.x;
  if (e < N_EDGES) atomicAdd(&counts[ei[N_EDGES + e]], 1);
}

__global__ __launch_bounds__(256) void scan_k(const int* __restrict__ counts,
                                              int* __restrict__ row_start,
                                              int* __restrict__ cursor) {
  __shared__ int sums[256];
  const int tid = threadIdx.x;
  const int CH = (N_NODES + 255) / 256;
  const int base = tid * CH;
  int s = 0;
  for (int i = 0; i < CH; ++i) {
    int n = base + i;
    if (n < N_NODES) s += counts[n];
  }
  sums[tid] = s;
  __syncthreads();
  if (tid == 0) {
    int acc = 0;
    for (int i = 0; i < 256; ++i) { int t = sums[i]; sums[i] = acc; acc += t; }
  }
  __syncthreads();
  int off = sums[tid];
  for (int i = 0; i < CH; ++i) {
    int n = base + i;
    if (n < N_NODES) {
      row_start[n] = off;
      cursor[n] = off;
      off += counts[n];
    }
  }
  if (tid == 255) row_start[N_NODES] = off;
}

__global__ __launch_bounds__(256) void perm_k(const int* __restrict__ ei,
                                              int* __restrict__ cursor,
                                              int* __restrict__ perm) {
  int e = blockIdx.x * 256 + threadIdx.x;
  if (e < N_EDGES) perm[e] = atomicAdd(&cursor[ei[N_EDGES + e]], 1);
}

// gather: agg[n] = sum of contiguous msg rows row_start[n]..row_start[n+1]
__global__ __launch_bounds__(256) void gather_k(const int* __restrict__ row_start,
                                                const ushortT* __restrict__ msg,
                                                ushortT* __restrict__ agg) {
  int node = blockIdx.x * 4 + (threadIdx.x >> 6);
  int lane = threadIdx.x & 63;
  if (node >= N_NODES) return;
  int a = row_start[node], b = row_start[node + 1];
  float s0 = 0.f, s1 = 0.f, s2 = 0.f, s3 = 0.f;
  for (int j = a; j < b; ++j) {
    uint2 u = *(const uint2*)(msg + (size_t)j * HID + lane * 4);
    s0 += bf2f(u.x & 0xFFFF); s1 += bf2f(u.x >> 16);
    s2 += bf2f(u.y & 0xFFFF); s3 += bf2f(u.y >> 16);
  }
  uint2 o;
  o.x = (uintT)f2bf(s0) | ((uintT)f2bf(s1) << 16);
  o.y = (uintT)f2bf(s2) | ((uintT)f2bf(s3) << 16);
  *(uint2*)(agg + (size_t)node * HID + lane * 4) = o;
}

// ---------------------------------------------------------------------------
// Weight prep: fp32 W[K,256] -> bf16 Wt[256,K], square 256x256 matrices
__global__ __launch_bounds__(256) void wconv_k(const float* __restrict__ src,
                                               ushortT* __restrict__ dst) {
  __shared__ float tile[64][65];
  const int b = blockIdx.x;
  const int mat = b >> 4, t = b & 15;
  const int tr = (t >> 2) * 64, tc = (t & 3) * 64;
  const float* S = src + (size_t)mat * HID * HID;
  ushortT* D = dst + (size_t)mat * HID * HID;
  const int tid = threadIdx.x;
#pragma unroll
  for (int i = 0; i < 16; ++i) {
    int idx = i * 256 + tid;
    int r = idx >> 6, c = idx & 63;
    tile[r][c] = S[(size_t)(tr + r) * HID + tc + c];
  }
  __syncthreads();
#pragma unroll
  for (int i = 0; i < 16; ++i) {
    int idx = i * 256 + tid;
    int n = idx >> 6, k = idx & 63;
    D[(size_t)(tc + n) * HID + tr + k] = f2bf(tile[k][n]);
  }
}

// mlp_w1 [L][50][256] fp32 -> w1t [L][256][64] bf16 (k padded with zeros)
__global__ __launch_bounds__(256) void w1conv_k(const float* __restrict__ src,
                                                ushortT* __restrict__ dst) {
  const int l = blockIdx.x;
  const int n = threadIdx.x;
  const float* S = src + (size_t)l * NGAUSS * HID;
  ushortT* D = dst + (size_t)l * HID * 64;
  for (int k = 0; k < 64; ++k) {
    float v = (k < NGAUSS) ? S[(size_t)k * HID + n] : 0.0f;
    D[(size_t)n * 64 + k] = f2bf(v);
  }
}

// ---------------------------------------------------------------------------
__global__ __launch_bounds__(256) void embed_k(const int* __restrict__ z,
                                               const float* __restrict__ emb,
                                               ushortT* __restrict__ h) {
  int idx = blockIdx.x * 256 + threadIdx.x;
  if (idx >= N_NODES * HID) return;
  int n = idx >> 8;
  int c = idx & 255;
  h[idx] = f2bf(emb[z[n] * HID + c]);
}

// LayerNorm + SiLU on p (fp32), write final fp32 output
__global__ __launch_bounds__(256) void ln_k(const float* __restrict__ p,
                                            const float* __restrict__ g,
                                            const float* __restrict__ b,
                                            float* __restrict__ out) {
  const int row = blockIdx.x;
  const int tid = threadIdx.x;
  const int wave = tid >> 6, lane = tid & 63;
  __shared__ float red[4], red2[4];

  float v = p[(size_t)row * HID + tid];
  float s = v;
#pragma unroll
  for (int m = 32; m; m >>= 1) s += __shfl_xor(s, m, 64);
  if (lane == 0) red[wave] = s;
  __syncthreads();
  float mu = (red[0] + red[1] + red[2] + red[3]) * (1.0f / 256.0f);
  float diff = v - mu;
  float qv = diff * diff;
#pragma unroll
  for (int m = 32; m; m >>= 1) qv += __shfl_xor(qv, m, 64);
  if (lane == 0) red2[wave] = qv;
  __syncthreads();
  float var = (red2[0] + red2[1] + red2[2] + red2[3]) * (1.0f / 256.0f);
  float y = diff * rsqrtf(var + 1e-5f) * g[tid] + b[tid];
  out[(size_t)row * HID + tid] = y * (1.0f / (1.0f + expf(-y)));
}

__global__ __launch_bounds__(256) void tail_k(const int* __restrict__ batch,
                                              float* __restrict__ out) {
  int i = blockIdx.x * 256 + threadIdx.x;
  if (i < N_NODES) out[i] = (float)batch[i];
}

// ---------------------------------------------------------------------------
extern "C" void kernel_launch(void* const* d_in, const int* in_sizes, int n_in,
                              void* d_out, int out_size, void* d_ws, size_t ws_size,
                              hipStream_t stream) {
  const int* z = (const int*)d_in[0];
  const float* pos = (const float*)d_in[1];
  const int* batch = (const int*)d_in[2];
  const int* ei = (const int*)d_in[3];
  const float* emb = (const float*)d_in[4];
  const float* mlp_w1 = (const float*)d_in[5];
  const float* mlp_b1 = (const float*)d_in[6];
  const float* mlp_w2 = (const float*)d_in[7];
  const float* mlp_b2 = (const float*)d_in[8];
  const float* lin1_w = (const float*)d_in[9];
  const float* lin2_w = (const float*)d_in[10];
  const float* lin2_b = (const float*)d_in[11];
  const float* lin_w = (const float*)d_in[12];
  const float* lin_b = (const float*)d_in[13];
  const float* proj_w = (const float*)d_in[14];
  const float* proj_b = (const float*)d_in[15];
  const float* ln_g = (const float*)d_in[16];
  const float* ln_b = (const float*)d_in[17];
  float* out = (float*)d_out;  // fp32: p [N*256] then batch [N]

  const size_t NH = (size_t)N_NODES * HID;
  const size_t EH = (size_t)N_EDGES * HID;
  const size_t WSZ = (size_t)HID * HID;

  // ---- workspace layout (~322 MB) ----
  char* w = (char*)d_ws;
  ushortT* h = (ushortT*)w;      w += NH * 2;
  ushortT* x1 = (ushortT*)w;     w += NH * 2;
  ushortT* agg = (ushortT*)w;    w += NH * 2;
  ushortT* msg = (ushortT*)w;                    // [E,H] bf16
  float* p = (float*)msg;                        // proj fp32 aliases msg
  w += EH * 2;
  ushortT* lin1t = (ushortT*)w;  w += 6 * WSZ * 2;
  ushortT* lin2t = (ushortT*)w;  w += 6 * WSZ * 2;
  ushortT* lint = (ushortT*)w;   w += 6 * WSZ * 2;
  ushortT* w2t = (ushortT*)w;    w += 6 * WSZ * 2;
  ushortT* projt = (ushortT*)w;  w += WSZ * 2;
  ushortT* w1t = (ushortT*)w;    w += 6 * (size_t)HID * 64 * 2;
  int* counts = (int*)w;         w += (size_t)N_NODES * 4;
  int* cursor = (int*)w;         w += (size_t)N_NODES * 4;
  int* row_start = (int*)w;      w += (size_t)(N_NODES + 64) * 4;
  int* perm = (int*)w;           w += (size_t)N_EDGES * 4;

  // ---- CSR build ----
  hipMemsetAsync(counts, 0, (size_t)N_NODES * 4, stream);
  hist_k<<<(N_EDGES + 255) / 256, 256, 0, stream>>>(ei, counts);
  scan_k<<<1, 256, 0, stream>>>(counts, row_start, cursor);
  perm_k<<<(N_EDGES + 255) / 256, 256, 0, stream>>>(ei, cursor, perm);

  // ---- weight prep ----
  wconv_k<<<6 * 16, 256, 0, stream>>>(lin1_w, lin1t);
  wconv_k<<<6 * 16, 256, 0, stream>>>(lin2_w, lin2t);
  wconv_k<<<6 * 16, 256, 0, stream>>>(lin_w, lint);
  wconv_k<<<6 * 16, 256, 0, stream>>>(mlp_w2, w2t);
  wconv_k<<<16, 256, 0, stream>>>(proj_w, projt);
  w1conv_k<<<6, 256, 0, stream>>>(mlp_w1, w1t);

  embed_k<<<(N_NODES * HID + 255) / 256, 256, 0, stream>>>(z, emb, h);

  const int MB = (N_NODES + 63) / 64;
  for (int l = 0; l < NLAYERS; ++l) {
    const size_t oW = (size_t)l * WSZ;
    const size_t o1 = (size_t)l * HID;
    mgemm<MODE_PLAIN><<<MB, 256, 0, stream>>>(h, lin1t + oW, nullptr, x1, nullptr, N_NODES);
    edge_mfma<<<N_EDGES / 64, 256, 0, stream>>>(ei, pos, perm, x1, msg,
                                                w1t + (size_t)l * HID * 64, mlp_b1 + o1,
                                                w2t + oW, mlp_b2 + o1);
    gather_k<<<(N_NODES + 3) / 4, 256, 0, stream>>>(row_start, msg, agg);
    mgemm<MODE_BIAS_SSP><<<MB, 256, 0, stream>>>(agg, lin2t + oW, lin2_b + o1, x1, nullptr, N_NODES);
    mgemm<MODE_BIAS_RESID><<<MB, 256, 0, stream>>>(x1, lint + oW, lin_b + o1, h, nullptr, N_NODES);
  }
  mgemm<MODE_PROJ><<<MB, 256, 0, stream>>>(h, projt, proj_b, nullptr, p, N_NODES);
  ln_k<<<N_NODES, 256, 0, stream>>>(p, ln_g, ln_b, out);
  tail_k<<<(N_NODES + 255) / 256, 256, 0, stream>>>(batch, out + NH);
}